// Round 3
// baseline (297.730 us; speedup 1.0000x reference)
//
#include <hip/hip_runtime.h>

// QuantileLoss: scalar = ( sum_rows[ (p0-t0)^2+(p1-t1)^2+(p2-t2)^2 + 2*lower ] ) / (5N)
// lower = p3>p2 ? 1000 : (p3 > 0.95*t2 ? 0 : (p3-0.95*t2)^2)
//
// R1 (row loads, no LDS):   101 us, eff 2.66 TB/s read
// R2 (LDS staged):          105 us
// R3 (NT 160B chunks):      150 us, 392 MB fetched (NT over-fetch)
// R4 (NT + pipeline):       ~95 us partial
// R5 (LDS, no atomics):     99.8 us, FETCH 134 MB (50% L3), occ 25%, eff 2.69 TB/s
// R6 (reg-only, no barrier):99.8 us, occ 65%, VGPR 20, eff 2.69 TB/s  <- identical
// Reads pin at ~2.7 TB/s across ALL structures; fill does 6.7 TB/s (writes) and
// float4 copy 6.29 TB/s combined (~3.15 TB/s read half). So attainable read-only
// is ~3.1 TB/s; we are at 85% of it. Remaining structural defect: burstiness --
// each wave issues 8 loads, drains vmcnt, computes, reduces, EXITS; pipe dead
// during compute+reduce+block relaunch.
// R7 (this): persistent 2048-block grid-stride + 2-deep register double-buffer:
// batch i+1's 8 independent dwordx4 loads issue BEFORE batch i's vmcnt wait
// (counted vmcnt keeps 8 in flight through compute), 4 batches/thread, one
// reduce+exit per 16 rows instead of per 4. If this is also ~100 us, the
// ~2.7-3.1 TB/s read cap is structural => roofline.

#define NROWS   8388608                     // 2^23
#define THREADS 256
#define GRID    2048                        // persistent: 8 blocks/CU
#define NGROUPS (NROWS / 4)                 // 2097152 groups of 4 rows
#define GSTRIDE ((size_t)GRID * THREADS)    // 524288 groups per pass
#define GPT     4                           // NGROUPS / GSTRIDE

typedef float v4f __attribute__((ext_vector_type(4)));

__device__ __forceinline__ void load_batch(const v4f* __restrict__ gp,
                                           const v4f* __restrict__ gt,
                                           size_t g, v4f P[5], v4f T[3])
{
    const v4f* p = gp + 5 * g;   // 4 rows of preds  = 5 aligned v4f
    const v4f* t = gt + 3 * g;   // 4 rows of target = 3 aligned v4f
    #pragma unroll
    for (int k = 0; k < 5; ++k) P[k] = p[k];
    #pragma unroll
    for (int k = 0; k < 3; ++k) T[k] = t[k];
}

__device__ __forceinline__ float compute_batch(const v4f P[5], const v4f T[3])
{
    float sum = 0.0f;
    #pragma unroll
    for (int r = 0; r < 4; ++r) {
        const float p0 = P[(5*r+0) >> 2][(5*r+0) & 3];
        const float p1 = P[(5*r+1) >> 2][(5*r+1) & 3];
        const float p2 = P[(5*r+2) >> 2][(5*r+2) & 3];
        const float p3 = P[(5*r+3) >> 2][(5*r+3) & 3];
        const float t0 = T[(3*r+0) >> 2][(3*r+0) & 3];
        const float t1 = T[(3*r+1) >> 2][(3*r+1) & 3];
        const float t2 = T[(3*r+2) >> 2][(3*r+2) & 3];

        const float a0 = p0 - t0;
        const float a1 = p1 - t1;
        const float a2 = p2 - t2;
        const float m  = a0*a0 + a1*a1 + a2*a2;

        const float q = t2 * 0.95f;
        const float d = p3 - q;
        const float lower = (p3 > p2) ? 1000.0f : ((p3 > q) ? 0.0f : d * d);

        sum += m + 2.0f * lower;
    }
    return sum;
}

__global__ void __launch_bounds__(256) qloss_partial(
    const float* __restrict__ preds,
    const float* __restrict__ target,
    double* __restrict__ ws)
{
    const int t = threadIdx.x;
    const size_t g0 = (size_t)blockIdx.x * THREADS + t;

    const v4f* gp = (const v4f*)preds;
    const v4f* gt = (const v4f*)target;

    // 2-deep register double-buffer; all indices compile-time (full unroll).
    v4f P[2][5], T[2][3];
    load_batch(gp, gt, g0, P[0], T[0]);

    double acc = 0.0;
    #pragma unroll
    for (int i = 0; i < GPT; ++i) {
        const int cur = i & 1;
        const int nxt = cur ^ 1;
        if (i + 1 < GPT)                               // issue next batch's 8 loads
            load_batch(gp, gt, g0 + (size_t)(i + 1) * GSTRIDE, P[nxt], T[nxt]);
        acc += (double)compute_batch(P[cur], T[cur]);  // waits only on batch i
    }

    // wave64 shuffle reduce -> per-block partial. No atomics.
    #pragma unroll
    for (int off = 32; off > 0; off >>= 1)
        acc += __shfl_down(acc, off, 64);

    __shared__ double red[4];
    const int lane = t & 63;
    const int wave = t >> 6;
    if (lane == 0) red[wave] = acc;
    __syncthreads();

    if (t == 0)
        ws[blockIdx.x] = red[0] + red[1] + red[2] + red[3];
}

__global__ void __launch_bounds__(256) qloss_final(
    const double* __restrict__ ws, float* __restrict__ out)
{
    const int t = threadIdx.x;
    double acc = 0.0;
    #pragma unroll
    for (int i = 0; i < GRID / 256; ++i)    // 8 partials/thread, 16 KB total
        acc += ws[t + i * 256];

    #pragma unroll
    for (int off = 32; off > 0; off >>= 1)
        acc += __shfl_down(acc, off, 64);

    __shared__ double red[4];
    const int lane = t & 63;
    const int wave = t >> 6;
    if (lane == 0) red[wave] = acc;
    __syncthreads();

    if (t == 0)
        *out = (float)((red[0] + red[1] + red[2] + red[3]) / (5.0 * (double)NROWS));
}

extern "C" void kernel_launch(void* const* d_in, const int* in_sizes, int n_in,
                              void* d_out, int out_size, void* d_ws, size_t ws_size,
                              hipStream_t stream)
{
    const float* preds  = (const float*)d_in[0];
    const float* target = (const float*)d_in[1];
    float* out  = (float*)d_out;
    double* ws  = (double*)d_ws;

    // Every ws slot [0, GRID) is overwritten by qloss_partial before qloss_final
    // reads it -> no memset needed despite workspace poisoning.
    qloss_partial<<<GRID, THREADS, 0, stream>>>(preds, target, ws);
    qloss_final<<<1, 256, 0, stream>>>(ws, out);
}

// Round 4
// 282.169 us; speedup vs baseline: 1.0551x; 1.0551x over previous
//
#include <hip/hip_runtime.h>

// QuantileLoss: scalar = ( sum_rows[ (p0-t0)^2+(p1-t1)^2+(p2-t2)^2 + 2*lower ] ) / (5N)
// lower = p3>p2 ? 1000 : (p3 > 0.95*t2 ? 0 : (p3-0.95*t2)^2)
//
// Ladder:
// R1 row loads cached:      101 us, eff read 2.66 TB/s (50% L3)
// R2 LDS staged cached:     105 us
// R3 NT 160B chunks:        150 us (1.46x NT over-fetch)
// R4 NT lane-contig + pipe:  95 us, eff 2.82 TB/s, 100% HBM  <- best partial
// R5 cached LDS, no atomic:  99.8 us, eff 2.69
// R6 reg-only no barrier:    99.8 us, occ 65% -> occupancy/burstiness not it
// R7 persistent dbuf:       105 us, FETCH up (L3 hit down) -> pipelining not it
// Conclusion so far: data-return to CUs pins ~2.7-2.8 TB/s from EITHER source;
// serial fit gives HBM~2.2-2.8, L3~3.5 component rates on a shared pipe.
// R8 (this): discriminating hybrid. R4's proven NT+LDS+pipeline structure,
// atomic-free tail, but preds (167.8 MB) via NT (HBM path, no L3 pollution)
// and target (100.7 MB) via cached loads (fits + stays in 256 MB L3).
//   shared-cap model -> ~95 us (then <<ROOFLINE>> next round)
//   serial-component -> ~89 us
//   parallel paths   -> ~60-65 us (then tune split)

#define NROWS 8388608                      // 2^23
#define ROWS_PER_CHUNK 1024
#define NCHUNKS (NROWS / ROWS_PER_CHUNK)   // 8192
#define PCHUNK (ROWS_PER_CHUNK * 5)        // 5120 floats = 20 KB
#define TCHUNK (ROWS_PER_CHUNK * 3)        // 3072 floats = 12 KB
#define GRID 2048
#define CHUNKS_PER_BLOCK (NCHUNKS / GRID)  // 4

typedef float v4f __attribute__((ext_vector_type(4)));

__global__ void __launch_bounds__(256) qloss_partial(
    const float* __restrict__ preds,
    const float* __restrict__ target,
    double* __restrict__ ws)
{
    __shared__ float sp[PCHUNK];
    __shared__ float st[TCHUNK];

    const int t = threadIdx.x;
    double acc = 0.0;

    // Prologue: chunk 0. preds NT (HBM path), target cached (L3 path).
    v4f rp[5], rt[3];
    {
        const v4f* gp = (const v4f*)(preds + (size_t)blockIdx.x * PCHUNK);
        const v4f* gt = (const v4f*)(target + (size_t)blockIdx.x * TCHUNK);
        #pragma unroll
        for (int k = 0; k < 5; ++k) rp[k] = __builtin_nontemporal_load(gp + t + k * 256);
        #pragma unroll
        for (int k = 0; k < 3; ++k) rt[k] = gt[t + k * 256];
    }

    #pragma unroll
    for (int i = 0; i < CHUNKS_PER_BLOCK; ++i) {
        // Stage current chunk into LDS (lane-contiguous, coalesced).
        #pragma unroll
        for (int k = 0; k < 5; ++k) ((v4f*)sp)[t + k * 256] = rp[k];
        #pragma unroll
        for (int k = 0; k < 3; ++k) ((v4f*)st)[t + k * 256] = rt[k];
        __syncthreads();

        // Next chunk's loads stay in flight during compute (2-stage pipeline).
        if (i + 1 < CHUNKS_PER_BLOCK) {
            const int nc = blockIdx.x + (i + 1) * GRID;
            const v4f* gp = (const v4f*)(preds + (size_t)nc * PCHUNK);
            const v4f* gt = (const v4f*)(target + (size_t)nc * TCHUNK);
            #pragma unroll
            for (int k = 0; k < 5; ++k) rp[k] = __builtin_nontemporal_load(gp + t + k * 256);
            #pragma unroll
            for (int k = 0; k < 3; ++k) rt[k] = gt[t + k * 256];
        }

        // Compute 4 rows/thread out of LDS (stride 5/3: 2-way bank alias, free).
        float sum = 0.0f;
        #pragma unroll
        for (int rr = 0; rr < 4; ++rr) {
            const int r = t + rr * 256;
            const float p0 = sp[5*r + 0];
            const float p1 = sp[5*r + 1];
            const float p2 = sp[5*r + 2];
            const float p3 = sp[5*r + 3];
            const float t0 = st[3*r + 0];
            const float t1 = st[3*r + 1];
            const float t2 = st[3*r + 2];

            const float a0 = p0 - t0;
            const float a1 = p1 - t1;
            const float a2 = p2 - t2;
            const float m  = a0*a0 + a1*a1 + a2*a2;

            const float q = t2 * 0.95f;
            const float d = p3 - q;
            const float lower = (p3 > p2) ? 1000.0f : ((p3 > q) ? 0.0f : d * d);

            sum += m + 2.0f * lower;
        }
        acc += (double)sum;
        __syncthreads();   // LDS safe to overwrite next iteration
    }

    // wave64 shuffle reduce -> per-block partial. No atomics, no memset needed.
    #pragma unroll
    for (int off = 32; off > 0; off >>= 1)
        acc += __shfl_down(acc, off, 64);

    __shared__ double red[4];
    const int lane = t & 63;
    const int wave = t >> 6;
    if (lane == 0) red[wave] = acc;
    __syncthreads();

    if (t == 0)
        ws[blockIdx.x] = red[0] + red[1] + red[2] + red[3];
}

__global__ void __launch_bounds__(256) qloss_final(
    const double* __restrict__ ws, float* __restrict__ out)
{
    const int t = threadIdx.x;
    double acc = 0.0;
    #pragma unroll
    for (int i = 0; i < GRID / 256; ++i)    // 8 partials/thread, 16 KB total
        acc += ws[t + i * 256];

    #pragma unroll
    for (int off = 32; off > 0; off >>= 1)
        acc += __shfl_down(acc, off, 64);

    __shared__ double red[4];
    const int lane = t & 63;
    const int wave = t >> 6;
    if (lane == 0) red[wave] = acc;
    __syncthreads();

    if (t == 0)
        *out = (float)((red[0] + red[1] + red[2] + red[3]) / (5.0 * (double)NROWS));
}

extern "C" void kernel_launch(void* const* d_in, const int* in_sizes, int n_in,
                              void* d_out, int out_size, void* d_ws, size_t ws_size,
                              hipStream_t stream)
{
    const float* preds  = (const float*)d_in[0];
    const float* target = (const float*)d_in[1];
    float* out  = (float*)d_out;
    double* ws  = (double*)d_ws;

    // Every ws slot [0, GRID) is overwritten by qloss_partial before qloss_final
    // reads it -> no memset needed despite workspace poisoning.
    qloss_partial<<<GRID, 256, 0, stream>>>(preds, target, ws);
    qloss_final<<<1, 256, 0, stream>>>(ws, out);
}